// Round 1
// baseline (1805.935 us; speedup 1.0000x reference)
//
#include <hip/hip_runtime.h>
#include <math.h>

#define NNODE 50000
#define NEDGE 800000
#define DINv  128
#define EDv   16
#define NHv   4
#define CHv   128
#define HCv   512
#define SLOPEv 0.2f

// ---------------------------------------------------------------- CSR build
__global__ void detect_kernel(const int* __restrict__ ei, int* __restrict__ flag) {
  // flag=1 if edge_index is int64 (high dwords of first 2048 entries all zero)
  __shared__ int bad;
  if (threadIdx.x == 0) bad = 0;
  __syncthreads();
  for (int i = threadIdx.x; i < 2048; i += 256)
    if (ei[2 * i + 1] != 0) bad = 1;
  __syncthreads();
  if (threadIdx.x == 0) flag[0] = bad ? 0 : 1;
}

__device__ __forceinline__ int load_idx(const int* __restrict__ ei, int e, int row, int wide) {
  if (wide) return ei[2 * ((size_t)row * NEDGE + e)];
  return ei[(size_t)row * NEDGE + e];
}

__global__ void count_kernel(const int* __restrict__ ei, const int* __restrict__ flag,
                             int* __restrict__ deg) {
  int e = blockIdx.x * blockDim.x + threadIdx.x;
  if (e < NEDGE) {
    int w = flag[0];
    atomicAdd(&deg[load_idx(ei, e, 1, w)], 1);
  }
}

__global__ __launch_bounds__(1024) void scan_kernel(const int* __restrict__ deg,
                                                    int* __restrict__ row_ptr) {
  __shared__ int buf[1024];
  __shared__ int carry;
  int tid = threadIdx.x;
  if (tid == 0) carry = 0;
  __syncthreads();
  for (int base = 0; base < NNODE; base += 1024) {
    int x = (base + tid < NNODE) ? deg[base + tid] : 0;
    buf[tid] = x;
    __syncthreads();
    for (int off = 1; off < 1024; off <<= 1) {
      int t = (tid >= off) ? buf[tid - off] : 0;
      __syncthreads();
      buf[tid] += t;
      __syncthreads();
    }
    if (base + tid < NNODE) row_ptr[base + tid] = carry + buf[tid] - x;
    __syncthreads();
    if (tid == 0) carry += buf[1023];
    __syncthreads();
  }
  if (tid == 0) row_ptr[NNODE] = carry;
}

__global__ void scatter_kernel(const int* __restrict__ ei, const int* __restrict__ flag,
                               const int* __restrict__ row_ptr, int* __restrict__ cursor,
                               int* __restrict__ src_sorted, int* __restrict__ eid_sorted) {
  int e = blockIdx.x * blockDim.x + threadIdx.x;
  if (e < NEDGE) {
    int w = flag[0];
    int d = load_idx(ei, e, 1, w);
    int s = load_idx(ei, e, 0, w);
    int p = row_ptr[d] + atomicAdd(&cursor[d], 1);
    src_sorted[p] = s;
    eid_sorted[p] = e;
  }
}

// ---------------------------------------------------------------- mean(edge_features)
__global__ void mean_kernel(const float* __restrict__ ea, float* __restrict__ mean_sum) {
  float acc[EDv];
#pragma unroll
  for (int d = 0; d < EDv; d++) acc[d] = 0.f;
  int stride = gridDim.x * blockDim.x;
  for (int r = blockIdx.x * blockDim.x + threadIdx.x; r < NEDGE; r += stride) {
    const float4* p = (const float4*)(ea + (size_t)r * EDv);
#pragma unroll
    for (int q = 0; q < 4; q++) {
      float4 v = p[q];
      acc[q * 4 + 0] += v.x; acc[q * 4 + 1] += v.y;
      acc[q * 4 + 2] += v.z; acc[q * 4 + 3] += v.w;
    }
  }
#pragma unroll
  for (int d = 0; d < EDv; d++) {
    float v = acc[d];
    for (int off = 32; off; off >>= 1) v += __shfl_down(v, off, 64);
    if ((threadIdx.x & 63) == 0) atomicAdd(&mean_sum[d], v);
  }
}

// ---------------------------------------------------------------- v = fold(We, a_e), loop_al_e
__global__ void vloop_kernel(const float* __restrict__ We, const float* __restrict__ a_e,
                             const float* __restrict__ mean_sum,
                             float* __restrict__ v, float* __restrict__ loop_al_e) {
  int t = threadIdx.x;  // 64 threads
  int d = t >> 2, h = t & 3;
  float s = 0.f;
  for (int c = 0; c < CHv; c++) s += We[(size_t)d * HCv + h * CHv + c] * a_e[h * CHv + c];
  v[d * 4 + h] = s;
  __syncthreads();
  if (t < NHv) {
    float acc = 0.f;
    for (int d2 = 0; d2 < EDv; d2++) acc += (mean_sum[d2] * (1.0f / NEDGE)) * v[d2 * 4 + t];
    loop_al_e[t] = acc;
  }
}

// ---------------------------------------------------------------- al_e = ea @ v   [E,4]
__global__ void ale_kernel(const float* __restrict__ ea, const float* __restrict__ v,
                           float* __restrict__ al_e) {
  __shared__ float sv[EDv * NHv];
  if (threadIdx.x < EDv * NHv) sv[threadIdx.x] = v[threadIdx.x];
  __syncthreads();
  int e = blockIdx.x * blockDim.x + threadIdx.x;
  if (e >= NEDGE) return;
  const float4* p = (const float4*)(ea + (size_t)e * EDv);
  float row[16];
  *(float4*)&row[0] = p[0]; *(float4*)&row[4] = p[1];
  *(float4*)&row[8] = p[2]; *(float4*)&row[12] = p[3];
  float o0 = 0, o1 = 0, o2 = 0, o3 = 0;
#pragma unroll
  for (int d = 0; d < 16; d++) {
    o0 += row[d] * sv[d * 4 + 0];
    o1 += row[d] * sv[d * 4 + 1];
    o2 += row[d] * sv[d * 4 + 2];
    o3 += row[d] * sv[d * 4 + 3];
  }
  ((float4*)al_e)[e] = make_float4(o0, o1, o2, o3);
}

// ---------------------------------------------------------------- f32 GEMM  C[M,512] = A[M,K] @ B[K,512]
#define BM 128
#define BN 128
#define BK 16
__global__ __launch_bounds__(256) void gemm_kernel(const float* __restrict__ A,
                                                   const float* __restrict__ B,
                                                   float* __restrict__ C, int M, int K) {
  __shared__ float As[BK][BM + 4];
  __shared__ float Bs[BK][BN];
  int tid = threadIdx.x;
  int tx = tid & 15, ty = tid >> 4;
  int rb = blockIdx.y * BM, cb = blockIdx.x * BN;
  float acc[8][8];
#pragma unroll
  for (int i = 0; i < 8; i++)
#pragma unroll
    for (int j = 0; j < 8; j++) acc[i][j] = 0.f;

  for (int k0 = 0; k0 < K; k0 += BK) {
#pragma unroll
    for (int s = 0; s < 2; s++) {
      int idx = (tid + s * 256) * 4;  // 0..2047
      int row = idx >> 4, kk = idx & 15;
      float4 va = make_float4(0.f, 0.f, 0.f, 0.f);
      if (rb + row < M) va = *(const float4*)(A + (size_t)(rb + row) * K + k0 + kk);
      As[kk + 0][row] = va.x; As[kk + 1][row] = va.y;
      As[kk + 2][row] = va.z; As[kk + 3][row] = va.w;
    }
#pragma unroll
    for (int s = 0; s < 2; s++) {
      int idx = (tid + s * 256) * 4;
      int kk = idx >> 7, n = idx & 127;
      *(float4*)&Bs[kk][n] = *(const float4*)(B + (size_t)(k0 + kk) * HCv + cb + n);
    }
    __syncthreads();
#pragma unroll
    for (int k = 0; k < BK; k++) {
      float a[8], b[8];
      *(float4*)&a[0] = *(float4*)&As[k][ty * 8];
      *(float4*)&a[4] = *(float4*)&As[k][ty * 8 + 4];
      *(float4*)&b[0] = *(float4*)&Bs[k][tx * 8];
      *(float4*)&b[4] = *(float4*)&Bs[k][tx * 8 + 4];
#pragma unroll
      for (int i = 0; i < 8; i++)
#pragma unroll
        for (int j = 0; j < 8; j++) acc[i][j] = fmaf(a[i], b[j], acc[i][j]);
    }
    __syncthreads();
  }
#pragma unroll
  for (int i = 0; i < 8; i++) {
    int r = rb + ty * 8 + i;
    if (r < M) {
      *(float4*)(C + (size_t)r * HCv + cb + tx * 8) =
          make_float4(acc[i][0], acc[i][1], acc[i][2], acc[i][3]);
      *(float4*)(C + (size_t)r * HCv + cb + tx * 8 + 4) =
          make_float4(acc[i][4], acc[i][5], acc[i][6], acc[i][7]);
    }
  }
}

// ---------------------------------------------------------------- al_src/al_dst from h
__global__ void rowdots_kernel(const float* __restrict__ h, const float* __restrict__ a_src,
                               const float* __restrict__ a_dst, float* __restrict__ al_src,
                               float* __restrict__ al_dst) {
  __shared__ float ssrc[HCv], sdst[HCv];
  int tid = threadIdx.x;  // 256
  for (int i = tid; i < HCv; i += 256) { ssrc[i] = a_src[i]; sdst[i] = a_dst[i]; }
  __syncthreads();
  int wave = tid >> 6, lane = tid & 63;
  int n = blockIdx.x * 4 + wave;
  if (n >= NNODE) return;
  const float4* hp = (const float4*)(h + (size_t)n * HCv);
  float s1 = 0.f, s2 = 0.f;
#pragma unroll
  for (int q = 0; q < 2; q++) {
    float4 v = hp[lane * 2 + q];
    int base = lane * 8 + q * 4;
    s1 += v.x * ssrc[base] + v.y * ssrc[base + 1] + v.z * ssrc[base + 2] + v.w * ssrc[base + 3];
    s2 += v.x * sdst[base] + v.y * sdst[base + 1] + v.z * sdst[base + 2] + v.w * sdst[base + 3];
  }
  for (int off = 8; off; off >>= 1) {
    s1 += __shfl_down(s1, off, 64);
    s2 += __shfl_down(s2, off, 64);
  }
  if ((lane & 15) == 0) {
    int head = lane >> 4;
    al_src[n * 4 + head] = s1;
    al_dst[n * 4 + head] = s2;
  }
}

// ---------------------------------------------------------------- per-node softmax + aggregate
#define CHKv 64
__global__ __launch_bounds__(256) void node_kernel(
    const float* __restrict__ h, const float* __restrict__ al_src,
    const float* __restrict__ al_dst, const float* __restrict__ al_e,
    const float* __restrict__ loop_al_e, const int* __restrict__ row_ptr,
    const int* __restrict__ src_sorted, const int* __restrict__ eid_sorted,
    const float* __restrict__ bias, float* __restrict__ out) {
  int n = blockIdx.x;
  int tid = threadIdx.x;
  int base = row_ptr[n];
  int deg = row_ptr[n + 1] - base;
  int wid = tid >> 6, lane = tid & 63;

  __shared__ int ssrc[CHKv];
  __shared__ float sw[CHKv][4];
  __shared__ float wm[4][4];
  __shared__ float wd[4][4];

  float4 aldv = *(const float4*)(al_dst + (size_t)n * 4);
  float ald[4] = {aldv.x, aldv.y, aldv.z, aldv.w};

  // self-loop alpha (same in all threads)
  float alp[4];
  {
    float4 as = *(const float4*)(al_src + (size_t)n * 4);
    float aa[4] = {as.x, as.y, as.z, as.w};
#pragma unroll
    for (int hh = 0; hh < 4; hh++) {
      float a = aa[hh] + ald[hh] + loop_al_e[hh];
      alp[hh] = a > 0.f ? a : SLOPEv * a;
    }
  }

  // ---- pass A: per-head max over edges (+ self loop)
  float mx[4] = {alp[0], alp[1], alp[2], alp[3]};
  for (int i = tid; i < deg; i += 256) {
    int s = src_sorted[base + i];
    int e = eid_sorted[base + i];
    float4 as = *(const float4*)(al_src + (size_t)s * 4);
    float4 ae = *(const float4*)(al_e + (size_t)e * 4);
    float av[4] = {as.x + ald[0] + ae.x, as.y + ald[1] + ae.y,
                   as.z + ald[2] + ae.z, as.w + ald[3] + ae.w};
#pragma unroll
    for (int hh = 0; hh < 4; hh++) {
      float a = av[hh] > 0.f ? av[hh] : SLOPEv * av[hh];
      mx[hh] = fmaxf(mx[hh], a);
    }
  }
#pragma unroll
  for (int hh = 0; hh < 4; hh++) {
    float v = mx[hh];
    for (int off = 32; off; off >>= 1) v = fmaxf(v, __shfl_down(v, off, 64));
    if (lane == 0) wm[wid][hh] = v;
  }
  __syncthreads();
  float m[4];
#pragma unroll
  for (int hh = 0; hh < 4; hh++)
    m[hh] = fmaxf(fmaxf(wm[0][hh], wm[1][hh]), fmaxf(wm[2][hh], wm[3][hh]));

  // ---- pass B: chunked exp + weighted gather
  int c0 = tid, c1 = tid + 256;
  int h0 = c0 >> 7, h1 = c1 >> 7;
  float acc0 = 0.f, acc1 = 0.f;
  float dpart[4] = {0.f, 0.f, 0.f, 0.f};

  for (int cs = 0; cs < deg; cs += CHKv) {
    int cl = min(CHKv, deg - cs);
    __syncthreads();
    if (tid < cl) {
      int s = src_sorted[base + cs + tid];
      int e = eid_sorted[base + cs + tid];
      float4 as = *(const float4*)(al_src + (size_t)s * 4);
      float4 ae = *(const float4*)(al_e + (size_t)e * 4);
      float av[4] = {as.x + ald[0] + ae.x, as.y + ald[1] + ae.y,
                     as.z + ald[2] + ae.z, as.w + ald[3] + ae.w};
      ssrc[tid] = s;
#pragma unroll
      for (int hh = 0; hh < 4; hh++) {
        float a = av[hh] > 0.f ? av[hh] : SLOPEv * av[hh];
        float w = expf(a - m[hh]);
        sw[tid][hh] = w;
        dpart[hh] += w;
      }
    }
    __syncthreads();
#pragma unroll 4
    for (int j = 0; j < cl; j++) {
      int s = ssrc[j];
      float w0 = sw[j][h0], w1 = sw[j][h1];
      acc0 = fmaf(w0, h[(size_t)s * HCv + c0], acc0);
      acc1 = fmaf(w1, h[(size_t)s * HCv + c1], acc1);
    }
  }

  // self-loop contribution
  float wl[4];
#pragma unroll
  for (int hh = 0; hh < 4; hh++) wl[hh] = expf(alp[hh] - m[hh]);
  if (tid == 0) {
#pragma unroll
    for (int hh = 0; hh < 4; hh++) dpart[hh] += wl[hh];
  }
  acc0 = fmaf(wl[h0], h[(size_t)n * HCv + c0], acc0);
  acc1 = fmaf(wl[h1], h[(size_t)n * HCv + c1], acc1);

  // reduce den
#pragma unroll
  for (int hh = 0; hh < 4; hh++) {
    float v = dpart[hh];
    for (int off = 32; off; off >>= 1) v += __shfl_down(v, off, 64);
    if (lane == 0) wd[wid][hh] = v;
  }
  __syncthreads();
  float den0 = wd[0][h0] + wd[1][h0] + wd[2][h0] + wd[3][h0];
  float den1 = wd[0][h1] + wd[1][h1] + wd[2][h1] + wd[3][h1];

  float r0 = acc0 / (den0 + 1e-16f) + bias[c0];
  float r1 = acc1 / (den1 + 1e-16f) + bias[c1];
  out[(size_t)n * HCv + c0] = r0 > 0.f ? r0 : expm1f(r0);
  out[(size_t)n * HCv + c1] = r1 > 0.f ? r1 : expm1f(r1);
}

// ---------------------------------------------------------------- launch
static inline char* take(char*& p, size_t bytes) {
  char* r = p;
  p += (bytes + 255) & ~(size_t)255;
  return r;
}

extern "C" void kernel_launch(void* const* d_in, const int* in_sizes, int n_in,
                              void* d_out, int out_size, void* d_ws, size_t ws_size,
                              hipStream_t stream) {
  (void)in_sizes; (void)n_in; (void)out_size; (void)ws_size;
  const float* x   = (const float*)d_in[0];
  const int*   ei  = (const int*)d_in[1];
  const float* ea  = (const float*)d_in[2];
  const float* W1  = (const float*)d_in[3];
  const float* as1 = (const float*)d_in[4];
  const float* ad1 = (const float*)d_in[5];
  const float* We1 = (const float*)d_in[6];
  const float* ae1 = (const float*)d_in[7];
  const float* b1  = (const float*)d_in[8];
  const float* W2  = (const float*)d_in[9];
  const float* as2 = (const float*)d_in[10];
  const float* ad2 = (const float*)d_in[11];
  const float* We2 = (const float*)d_in[12];
  const float* ae2 = (const float*)d_in[13];
  const float* b2  = (const float*)d_in[14];
  float* out = (float*)d_out;

  char* p = (char*)d_ws;
  float* h          = (float*)take(p, (size_t)NNODE * HCv * 4);
  float* al_src     = (float*)take(p, (size_t)NNODE * 4 * 4);
  float* al_dst     = (float*)take(p, (size_t)NNODE * 4 * 4);
  float* al_e       = (float*)take(p, (size_t)NEDGE * 4 * 4);
  int*   src_sorted = (int*)take(p, (size_t)NEDGE * 4);
  int*   eid_sorted = (int*)take(p, (size_t)NEDGE * 4);
  int*   row_ptr    = (int*)take(p, (size_t)(NNODE + 1) * 4);
  char* zero_begin = p;
  int*   deg        = (int*)take(p, (size_t)NNODE * 4);
  int*   cursor     = (int*)take(p, (size_t)NNODE * 4);
  float* mean_sum   = (float*)take(p, 16 * 4);
  size_t zero_len = (size_t)(p - zero_begin);
  float* v          = (float*)take(p, 64 * 4);
  float* loop_ale   = (float*)take(p, 4 * 4);
  int*   flag       = (int*)take(p, 4);

  hipMemsetAsync(zero_begin, 0, zero_len, stream);

  detect_kernel<<<1, 256, 0, stream>>>(ei, flag);
  count_kernel<<<(NEDGE + 255) / 256, 256, 0, stream>>>(ei, flag, deg);
  scan_kernel<<<1, 1024, 0, stream>>>(deg, row_ptr);
  scatter_kernel<<<(NEDGE + 255) / 256, 256, 0, stream>>>(ei, flag, row_ptr, cursor,
                                                          src_sorted, eid_sorted);
  mean_kernel<<<512, 256, 0, stream>>>(ea, mean_sum);

  // ---- layer 1
  vloop_kernel<<<1, 64, 0, stream>>>(We1, ae1, mean_sum, v, loop_ale);
  ale_kernel<<<(NEDGE + 255) / 256, 256, 0, stream>>>(ea, v, al_e);
  gemm_kernel<<<dim3(HCv / BN, (NNODE + BM - 1) / BM), 256, 0, stream>>>(x, W1, h, NNODE, DINv);
  rowdots_kernel<<<(NNODE + 3) / 4, 256, 0, stream>>>(h, as1, ad1, al_src, al_dst);
  node_kernel<<<NNODE, 256, 0, stream>>>(h, al_src, al_dst, al_e, loop_ale, row_ptr,
                                         src_sorted, eid_sorted, b1, out);

  // ---- layer 2 (input = out, overwritten only after all reads)
  vloop_kernel<<<1, 64, 0, stream>>>(We2, ae2, mean_sum, v, loop_ale);
  ale_kernel<<<(NEDGE + 255) / 256, 256, 0, stream>>>(ea, v, al_e);
  gemm_kernel<<<dim3(HCv / BN, (NNODE + BM - 1) / BM), 256, 0, stream>>>(out, W2, h, NNODE, HCv);
  rowdots_kernel<<<(NNODE + 3) / 4, 256, 0, stream>>>(h, as2, ad2, al_src, al_dst);
  node_kernel<<<NNODE, 256, 0, stream>>>(h, al_src, al_dst, al_e, loop_ale, row_ptr,
                                         src_sorted, eid_sorted, b2, out);
}

// Round 2
// 1381.645 us; speedup vs baseline: 1.3071x; 1.3071x over previous
//
#include <hip/hip_runtime.h>
#include <math.h>

#define NNODE 50000
#define NEDGE 800000
#define DINv  128
#define EDv   16
#define NHv   4
#define CHv   128
#define HCv   512
#define SLOPEv 0.2f
#define MEANBLK 512

// ---------------------------------------------------------------- CSR build
__global__ void detect_kernel(const int* __restrict__ ei, int* __restrict__ flag) {
  // flag=1 if edge_index is int64 (high dwords of first 2048 entries all zero)
  __shared__ int bad;
  if (threadIdx.x == 0) bad = 0;
  __syncthreads();
  for (int i = threadIdx.x; i < 2048; i += 256)
    if (ei[2 * i + 1] != 0) bad = 1;
  __syncthreads();
  if (threadIdx.x == 0) flag[0] = bad ? 0 : 1;
}

__device__ __forceinline__ int load_idx(const int* __restrict__ ei, int e, int row, int wide) {
  if (wide) return ei[2 * ((size_t)row * NEDGE + e)];
  return ei[(size_t)row * NEDGE + e];
}

__global__ void count_kernel(const int* __restrict__ ei, const int* __restrict__ flag,
                             int* __restrict__ deg) {
  int e = blockIdx.x * blockDim.x + threadIdx.x;
  if (e < NEDGE) {
    int w = flag[0];
    atomicAdd(&deg[load_idx(ei, e, 1, w)], 1);
  }
}

__global__ __launch_bounds__(1024) void scan_kernel(const int* __restrict__ deg,
                                                    int* __restrict__ row_ptr) {
  __shared__ int buf[1024];
  __shared__ int carry;
  int tid = threadIdx.x;
  if (tid == 0) carry = 0;
  __syncthreads();
  for (int base = 0; base < NNODE; base += 1024) {
    int x = (base + tid < NNODE) ? deg[base + tid] : 0;
    buf[tid] = x;
    __syncthreads();
    for (int off = 1; off < 1024; off <<= 1) {
      int t = (tid >= off) ? buf[tid - off] : 0;
      __syncthreads();
      buf[tid] += t;
      __syncthreads();
    }
    if (base + tid < NNODE) row_ptr[base + tid] = carry + buf[tid] - x;
    __syncthreads();
    if (tid == 0) carry += buf[1023];
    __syncthreads();
  }
  if (tid == 0) row_ptr[NNODE] = carry;
}

__global__ void scatter_kernel(const int* __restrict__ ei, const int* __restrict__ flag,
                               const int* __restrict__ row_ptr, int* __restrict__ cursor,
                               int* __restrict__ src_sorted, int* __restrict__ eid_sorted) {
  int e = blockIdx.x * blockDim.x + threadIdx.x;
  if (e < NEDGE) {
    int w = flag[0];
    int d = load_idx(ei, e, 1, w);
    int s = load_idx(ei, e, 0, w);
    int p = row_ptr[d] + atomicAdd(&cursor[d], 1);
    src_sorted[p] = s;
    eid_sorted[p] = e;
  }
}

// ---------------------------------------------------------------- mean(edge_features)
// two-stage: per-block partials (no atomics), then one-block fold
__global__ void mean_part_kernel(const float* __restrict__ ea, float* __restrict__ partials) {
  float acc[EDv];
#pragma unroll
  for (int d = 0; d < EDv; d++) acc[d] = 0.f;
  int stride = gridDim.x * blockDim.x;
  for (int r = blockIdx.x * blockDim.x + threadIdx.x; r < NEDGE; r += stride) {
    const float4* p = (const float4*)(ea + (size_t)r * EDv);
#pragma unroll
    for (int q = 0; q < 4; q++) {
      float4 v = p[q];
      acc[q * 4 + 0] += v.x; acc[q * 4 + 1] += v.y;
      acc[q * 4 + 2] += v.z; acc[q * 4 + 3] += v.w;
    }
  }
  __shared__ float red[4][EDv];  // one slot per wave
  int wid = threadIdx.x >> 6, lane = threadIdx.x & 63;
#pragma unroll
  for (int d = 0; d < EDv; d++) {
    float v = acc[d];
    for (int off = 32; off; off >>= 1) v += __shfl_down(v, off, 64);
    if (lane == 0) red[wid][d] = v;
  }
  __syncthreads();
  if (threadIdx.x < EDv) {
    float v = red[0][threadIdx.x] + red[1][threadIdx.x] + red[2][threadIdx.x] + red[3][threadIdx.x];
    partials[blockIdx.x * EDv + threadIdx.x] = v;
  }
}

__global__ void mean_fold_kernel(const float* __restrict__ partials, float* __restrict__ mean_sum) {
  // 256 threads: 16 threads per column (d = tid&15), rows strided by 16
  int tid = threadIdx.x;
  int d = tid & 15, r0 = tid >> 4;
  float v = 0.f;
  for (int r = r0; r < MEANBLK; r += 16) v += partials[r * EDv + d];
  __shared__ float buf[256];
  buf[tid] = v;
  __syncthreads();
  if (r0 < 8) buf[tid] += buf[tid + 128];
  __syncthreads();
  if (r0 < 4) buf[tid] += buf[tid + 64];
  __syncthreads();
  if (r0 < 2) buf[tid] += buf[tid + 32];
  __syncthreads();
  if (r0 == 0) mean_sum[d] = buf[tid] + buf[tid + 16];
}

// ---------------------------------------------------------------- v = fold(We, a_e), loop_al_e
__global__ void vloop_kernel(const float* __restrict__ We, const float* __restrict__ a_e,
                             const float* __restrict__ mean_sum,
                             float* __restrict__ v, float* __restrict__ loop_al_e) {
  int t = threadIdx.x;  // 64 threads
  int d = t >> 2, h = t & 3;
  float s = 0.f;
  for (int c = 0; c < CHv; c++) s += We[(size_t)d * HCv + h * CHv + c] * a_e[h * CHv + c];
  v[d * 4 + h] = s;
  __syncthreads();
  if (t < NHv) {
    float acc = 0.f;
    for (int d2 = 0; d2 < EDv; d2++) acc += (mean_sum[d2] * (1.0f / NEDGE)) * v[d2 * 4 + t];
    loop_al_e[t] = acc;
  }
}

// ---------------------------------------------------------------- al_e = ea @ v   [E,4]
__global__ void ale_kernel(const float* __restrict__ ea, const float* __restrict__ v,
                           float* __restrict__ al_e) {
  __shared__ float sv[EDv * NHv];
  if (threadIdx.x < EDv * NHv) sv[threadIdx.x] = v[threadIdx.x];
  __syncthreads();
  int e = blockIdx.x * blockDim.x + threadIdx.x;
  if (e >= NEDGE) return;
  const float4* p = (const float4*)(ea + (size_t)e * EDv);
  float row[16];
  *(float4*)&row[0] = p[0]; *(float4*)&row[4] = p[1];
  *(float4*)&row[8] = p[2]; *(float4*)&row[12] = p[3];
  float o0 = 0, o1 = 0, o2 = 0, o3 = 0;
#pragma unroll
  for (int d = 0; d < 16; d++) {
    o0 += row[d] * sv[d * 4 + 0];
    o1 += row[d] * sv[d * 4 + 1];
    o2 += row[d] * sv[d * 4 + 2];
    o3 += row[d] * sv[d * 4 + 3];
  }
  ((float4*)al_e)[e] = make_float4(o0, o1, o2, o3);
}

// ---------------------------------------------------------------- f32 GEMM  C[M,512] = A[M,K] @ B[K,512]
#define BM 128
#define BN 128
#define BK 16
__global__ __launch_bounds__(256) void gemm_kernel(const float* __restrict__ A,
                                                   const float* __restrict__ B,
                                                   float* __restrict__ C, int M, int K) {
  __shared__ float As[BK][BM + 4];
  __shared__ float Bs[BK][BN];
  int tid = threadIdx.x;
  int tx = tid & 15, ty = tid >> 4;
  int rb = blockIdx.y * BM, cb = blockIdx.x * BN;
  float acc[8][8];
#pragma unroll
  for (int i = 0; i < 8; i++)
#pragma unroll
    for (int j = 0; j < 8; j++) acc[i][j] = 0.f;

  for (int k0 = 0; k0 < K; k0 += BK) {
#pragma unroll
    for (int s = 0; s < 2; s++) {
      int idx = (tid + s * 256) * 4;  // 0..2047
      int row = idx >> 4, kk = idx & 15;
      float4 va = make_float4(0.f, 0.f, 0.f, 0.f);
      if (rb + row < M) va = *(const float4*)(A + (size_t)(rb + row) * K + k0 + kk);
      As[kk + 0][row] = va.x; As[kk + 1][row] = va.y;
      As[kk + 2][row] = va.z; As[kk + 3][row] = va.w;
    }
#pragma unroll
    for (int s = 0; s < 2; s++) {
      int idx = (tid + s * 256) * 4;
      int kk = idx >> 7, n = idx & 127;
      *(float4*)&Bs[kk][n] = *(const float4*)(B + (size_t)(k0 + kk) * HCv + cb + n);
    }
    __syncthreads();
#pragma unroll
    for (int k = 0; k < BK; k++) {
      float a[8], b[8];
      *(float4*)&a[0] = *(float4*)&As[k][ty * 8];
      *(float4*)&a[4] = *(float4*)&As[k][ty * 8 + 4];
      *(float4*)&b[0] = *(float4*)&Bs[k][tx * 8];
      *(float4*)&b[4] = *(float4*)&Bs[k][tx * 8 + 4];
#pragma unroll
      for (int i = 0; i < 8; i++)
#pragma unroll
        for (int j = 0; j < 8; j++) acc[i][j] = fmaf(a[i], b[j], acc[i][j]);
    }
    __syncthreads();
  }
#pragma unroll
  for (int i = 0; i < 8; i++) {
    int r = rb + ty * 8 + i;
    if (r < M) {
      *(float4*)(C + (size_t)r * HCv + cb + tx * 8) =
          make_float4(acc[i][0], acc[i][1], acc[i][2], acc[i][3]);
      *(float4*)(C + (size_t)r * HCv + cb + tx * 8 + 4) =
          make_float4(acc[i][4], acc[i][5], acc[i][6], acc[i][7]);
    }
  }
}

// ---------------------------------------------------------------- al_src/al_dst from h
__global__ void rowdots_kernel(const float* __restrict__ h, const float* __restrict__ a_src,
                               const float* __restrict__ a_dst, float* __restrict__ al_src,
                               float* __restrict__ al_dst) {
  __shared__ float ssrc[HCv], sdst[HCv];
  int tid = threadIdx.x;  // 256
  for (int i = tid; i < HCv; i += 256) { ssrc[i] = a_src[i]; sdst[i] = a_dst[i]; }
  __syncthreads();
  int wave = tid >> 6, lane = tid & 63;
  int n = blockIdx.x * 4 + wave;
  if (n >= NNODE) return;
  const float4* hp = (const float4*)(h + (size_t)n * HCv);
  float s1 = 0.f, s2 = 0.f;
#pragma unroll
  for (int q = 0; q < 2; q++) {
    float4 v = hp[lane * 2 + q];
    int base = lane * 8 + q * 4;
    s1 += v.x * ssrc[base] + v.y * ssrc[base + 1] + v.z * ssrc[base + 2] + v.w * ssrc[base + 3];
    s2 += v.x * sdst[base] + v.y * sdst[base + 1] + v.z * sdst[base + 2] + v.w * sdst[base + 3];
  }
  for (int off = 8; off; off >>= 1) {
    s1 += __shfl_down(s1, off, 64);
    s2 += __shfl_down(s2, off, 64);
  }
  if ((lane & 15) == 0) {
    int head = lane >> 4;
    al_src[n * 4 + head] = s1;
    al_dst[n * 4 + head] = s2;
  }
}

// ---------------------------------------------------------------- per-node softmax + aggregate
#define CHKv 64
__global__ __launch_bounds__(256) void node_kernel(
    const float* __restrict__ h, const float* __restrict__ al_src,
    const float* __restrict__ al_dst, const float* __restrict__ al_e,
    const float* __restrict__ loop_al_e, const int* __restrict__ row_ptr,
    const int* __restrict__ src_sorted, const int* __restrict__ eid_sorted,
    const float* __restrict__ bias, float* __restrict__ out) {
  int n = blockIdx.x;
  int tid = threadIdx.x;
  int base = row_ptr[n];
  int deg = row_ptr[n + 1] - base;
  int wid = tid >> 6, lane = tid & 63;

  __shared__ int ssrc[CHKv];
  __shared__ float sw[CHKv][4];
  __shared__ float wm[4][4];
  __shared__ float wd[4][4];

  float4 aldv = *(const float4*)(al_dst + (size_t)n * 4);
  float ald[4] = {aldv.x, aldv.y, aldv.z, aldv.w};

  // self-loop alpha (same in all threads)
  float alp[4];
  {
    float4 as = *(const float4*)(al_src + (size_t)n * 4);
    float aa[4] = {as.x, as.y, as.z, as.w};
#pragma unroll
    for (int hh = 0; hh < 4; hh++) {
      float a = aa[hh] + ald[hh] + loop_al_e[hh];
      alp[hh] = a > 0.f ? a : SLOPEv * a;
    }
  }

  // ---- pass A: per-head max over edges (+ self loop)
  float mx[4] = {alp[0], alp[1], alp[2], alp[3]};
  for (int i = tid; i < deg; i += 256) {
    int s = src_sorted[base + i];
    int e = eid_sorted[base + i];
    float4 as = *(const float4*)(al_src + (size_t)s * 4);
    float4 ae = *(const float4*)(al_e + (size_t)e * 4);
    float av[4] = {as.x + ald[0] + ae.x, as.y + ald[1] + ae.y,
                   as.z + ald[2] + ae.z, as.w + ald[3] + ae.w};
#pragma unroll
    for (int hh = 0; hh < 4; hh++) {
      float a = av[hh] > 0.f ? av[hh] : SLOPEv * av[hh];
      mx[hh] = fmaxf(mx[hh], a);
    }
  }
#pragma unroll
  for (int hh = 0; hh < 4; hh++) {
    float v = mx[hh];
    for (int off = 32; off; off >>= 1) v = fmaxf(v, __shfl_down(v, off, 64));
    if (lane == 0) wm[wid][hh] = v;
  }
  __syncthreads();
  float m[4];
#pragma unroll
  for (int hh = 0; hh < 4; hh++)
    m[hh] = fmaxf(fmaxf(wm[0][hh], wm[1][hh]), fmaxf(wm[2][hh], wm[3][hh]));

  // ---- pass B: chunked exp + weighted gather
  int c0 = tid, c1 = tid + 256;
  int h0 = c0 >> 7, h1 = c1 >> 7;
  float acc0 = 0.f, acc1 = 0.f;
  float dpart[4] = {0.f, 0.f, 0.f, 0.f};

  for (int cs = 0; cs < deg; cs += CHKv) {
    int cl = min(CHKv, deg - cs);
    __syncthreads();
    if (tid < cl) {
      int s = src_sorted[base + cs + tid];
      int e = eid_sorted[base + cs + tid];
      float4 as = *(const float4*)(al_src + (size_t)s * 4);
      float4 ae = *(const float4*)(al_e + (size_t)e * 4);
      float av[4] = {as.x + ald[0] + ae.x, as.y + ald[1] + ae.y,
                     as.z + ald[2] + ae.z, as.w + ald[3] + ae.w};
      ssrc[tid] = s;
#pragma unroll
      for (int hh = 0; hh < 4; hh++) {
        float a = av[hh] > 0.f ? av[hh] : SLOPEv * av[hh];
        float w = expf(a - m[hh]);
        sw[tid][hh] = w;
        dpart[hh] += w;
      }
    }
    __syncthreads();
#pragma unroll 4
    for (int j = 0; j < cl; j++) {
      int s = ssrc[j];
      float w0 = sw[j][h0], w1 = sw[j][h1];
      acc0 = fmaf(w0, h[(size_t)s * HCv + c0], acc0);
      acc1 = fmaf(w1, h[(size_t)s * HCv + c1], acc1);
    }
  }

  // self-loop contribution
  float wl[4];
#pragma unroll
  for (int hh = 0; hh < 4; hh++) wl[hh] = expf(alp[hh] - m[hh]);
  if (tid == 0) {
#pragma unroll
    for (int hh = 0; hh < 4; hh++) dpart[hh] += wl[hh];
  }
  acc0 = fmaf(wl[h0], h[(size_t)n * HCv + c0], acc0);
  acc1 = fmaf(wl[h1], h[(size_t)n * HCv + c1], acc1);

  // reduce den
#pragma unroll
  for (int hh = 0; hh < 4; hh++) {
    float v = dpart[hh];
    for (int off = 32; off; off >>= 1) v += __shfl_down(v, off, 64);
    if (lane == 0) wd[wid][hh] = v;
  }
  __syncthreads();
  float den0 = wd[0][h0] + wd[1][h0] + wd[2][h0] + wd[3][h0];
  float den1 = wd[0][h1] + wd[1][h1] + wd[2][h1] + wd[3][h1];

  float r0 = acc0 / (den0 + 1e-16f) + bias[c0];
  float r1 = acc1 / (den1 + 1e-16f) + bias[c1];
  out[(size_t)n * HCv + c0] = r0 > 0.f ? r0 : expm1f(r0);
  out[(size_t)n * HCv + c1] = r1 > 0.f ? r1 : expm1f(r1);
}

// ---------------------------------------------------------------- launch
static inline char* take(char*& p, size_t bytes) {
  char* r = p;
  p += (bytes + 255) & ~(size_t)255;
  return r;
}

extern "C" void kernel_launch(void* const* d_in, const int* in_sizes, int n_in,
                              void* d_out, int out_size, void* d_ws, size_t ws_size,
                              hipStream_t stream) {
  (void)in_sizes; (void)n_in; (void)out_size; (void)ws_size;
  const float* x   = (const float*)d_in[0];
  const int*   ei  = (const int*)d_in[1];
  const float* ea  = (const float*)d_in[2];
  const float* W1  = (const float*)d_in[3];
  const float* as1 = (const float*)d_in[4];
  const float* ad1 = (const float*)d_in[5];
  const float* We1 = (const float*)d_in[6];
  const float* ae1 = (const float*)d_in[7];
  const float* b1  = (const float*)d_in[8];
  const float* W2  = (const float*)d_in[9];
  const float* as2 = (const float*)d_in[10];
  const float* ad2 = (const float*)d_in[11];
  const float* We2 = (const float*)d_in[12];
  const float* ae2 = (const float*)d_in[13];
  const float* b2  = (const float*)d_in[14];
  float* out = (float*)d_out;

  char* p = (char*)d_ws;
  float* h          = (float*)take(p, (size_t)NNODE * HCv * 4);
  float* al_src     = (float*)take(p, (size_t)NNODE * 4 * 4);
  float* al_dst     = (float*)take(p, (size_t)NNODE * 4 * 4);
  float* al_e       = (float*)take(p, (size_t)NEDGE * 4 * 4);
  int*   src_sorted = (int*)take(p, (size_t)NEDGE * 4);
  int*   eid_sorted = (int*)take(p, (size_t)NEDGE * 4);
  int*   row_ptr    = (int*)take(p, (size_t)(NNODE + 1) * 4);
  float* partials   = (float*)take(p, (size_t)MEANBLK * EDv * 4);
  char* zero_begin = p;
  int*   deg        = (int*)take(p, (size_t)NNODE * 4);
  int*   cursor     = (int*)take(p, (size_t)NNODE * 4);
  size_t zero_len = (size_t)(p - zero_begin);
  float* mean_sum   = (float*)take(p, 16 * 4);
  float* v          = (float*)take(p, 64 * 4);
  float* loop_ale   = (float*)take(p, 4 * 4);
  int*   flag       = (int*)take(p, 4);

  hipMemsetAsync(zero_begin, 0, zero_len, stream);

  detect_kernel<<<1, 256, 0, stream>>>(ei, flag);
  count_kernel<<<(NEDGE + 255) / 256, 256, 0, stream>>>(ei, flag, deg);
  scan_kernel<<<1, 1024, 0, stream>>>(deg, row_ptr);
  scatter_kernel<<<(NEDGE + 255) / 256, 256, 0, stream>>>(ei, flag, row_ptr, cursor,
                                                          src_sorted, eid_sorted);
  mean_part_kernel<<<MEANBLK, 256, 0, stream>>>(ea, partials);
  mean_fold_kernel<<<1, 256, 0, stream>>>(partials, mean_sum);

  // ---- layer 1
  vloop_kernel<<<1, 64, 0, stream>>>(We1, ae1, mean_sum, v, loop_ale);
  ale_kernel<<<(NEDGE + 255) / 256, 256, 0, stream>>>(ea, v, al_e);
  gemm_kernel<<<dim3(HCv / BN, (NNODE + BM - 1) / BM), 256, 0, stream>>>(x, W1, h, NNODE, DINv);
  rowdots_kernel<<<(NNODE + 3) / 4, 256, 0, stream>>>(h, as1, ad1, al_src, al_dst);
  node_kernel<<<NNODE, 256, 0, stream>>>(h, al_src, al_dst, al_e, loop_ale, row_ptr,
                                         src_sorted, eid_sorted, b1, out);

  // ---- layer 2 (input = out, overwritten only after all reads)
  vloop_kernel<<<1, 64, 0, stream>>>(We2, ae2, mean_sum, v, loop_ale);
  ale_kernel<<<(NEDGE + 255) / 256, 256, 0, stream>>>(ea, v, al_e);
  gemm_kernel<<<dim3(HCv / BN, (NNODE + BM - 1) / BM), 256, 0, stream>>>(out, W2, h, NNODE, HCv);
  rowdots_kernel<<<(NNODE + 3) / 4, 256, 0, stream>>>(h, as2, ad2, al_src, al_dst);
  node_kernel<<<NNODE, 256, 0, stream>>>(h, al_src, al_dst, al_e, loop_ale, row_ptr,
                                         src_sorted, eid_sorted, b2, out);
}

// Round 3
// 1058.542 us; speedup vs baseline: 1.7061x; 1.3052x over previous
//
#include <hip/hip_runtime.h>
#include <math.h>

#define NNODE 50000
#define NEDGE 800000
#define DINv  128
#define EDv   16
#define NHv   4
#define CHv   128
#define HCv   512
#define SLOPEv 0.2f
#define MEANBLK 512

typedef __attribute__((ext_vector_type(8))) short bf16x8;
typedef __attribute__((ext_vector_type(4))) float f32x4;
typedef __attribute__((address_space(3))) unsigned lds_u32;
typedef const __attribute__((address_space(1))) unsigned glb_u32;

__device__ __forceinline__ ushort f2b(float f) {
  unsigned u = __float_as_uint(f);
  u += 0x7FFF + ((u >> 16) & 1);
  return (ushort)(u >> 16);
}

// ---------------------------------------------------------------- CSR build
__global__ void detect_kernel(const int* __restrict__ ei, int* __restrict__ flag) {
  __shared__ int bad;
  if (threadIdx.x == 0) bad = 0;
  __syncthreads();
  for (int i = threadIdx.x; i < 2048; i += 256)
    if (ei[2 * i + 1] != 0) bad = 1;
  __syncthreads();
  if (threadIdx.x == 0) flag[0] = bad ? 0 : 1;
}

__device__ __forceinline__ int load_idx(const int* __restrict__ ei, int e, int row, int wide) {
  if (wide) return ei[2 * ((size_t)row * NEDGE + e)];
  return ei[(size_t)row * NEDGE + e];
}

__global__ void count_kernel(const int* __restrict__ ei, const int* __restrict__ flag,
                             int* __restrict__ deg) {
  int e = blockIdx.x * blockDim.x + threadIdx.x;
  if (e < NEDGE) {
    int w = flag[0];
    atomicAdd(&deg[load_idx(ei, e, 1, w)], 1);
  }
}

__global__ __launch_bounds__(1024) void scan_kernel(const int* __restrict__ deg,
                                                    int* __restrict__ row_ptr) {
  __shared__ int buf[1024];
  __shared__ int carry;
  int tid = threadIdx.x;
  if (tid == 0) carry = 0;
  __syncthreads();
  for (int base = 0; base < NNODE; base += 1024) {
    int x = (base + tid < NNODE) ? deg[base + tid] : 0;
    buf[tid] = x;
    __syncthreads();
    for (int off = 1; off < 1024; off <<= 1) {
      int t = (tid >= off) ? buf[tid - off] : 0;
      __syncthreads();
      buf[tid] += t;
      __syncthreads();
    }
    if (base + tid < NNODE) row_ptr[base + tid] = carry + buf[tid] - x;
    __syncthreads();
    if (tid == 0) carry += buf[1023];
    __syncthreads();
  }
  if (tid == 0) row_ptr[NNODE] = carry;
}

__global__ void scatter_kernel(const int* __restrict__ ei, const int* __restrict__ flag,
                               const int* __restrict__ row_ptr, int* __restrict__ cursor,
                               int* __restrict__ src_sorted, int* __restrict__ eid_sorted) {
  int e = blockIdx.x * blockDim.x + threadIdx.x;
  if (e < NEDGE) {
    int w = flag[0];
    int d = load_idx(ei, e, 1, w);
    int s = load_idx(ei, e, 0, w);
    int p = row_ptr[d] + atomicAdd(&cursor[d], 1);
    src_sorted[p] = s;
    eid_sorted[p] = e;
  }
}

// ---------------------------------------------------------------- mean(edge_features)
__global__ void mean_part_kernel(const float* __restrict__ ea, float* __restrict__ partials) {
  float acc[EDv];
#pragma unroll
  for (int d = 0; d < EDv; d++) acc[d] = 0.f;
  int stride = gridDim.x * blockDim.x;
  for (int r = blockIdx.x * blockDim.x + threadIdx.x; r < NEDGE; r += stride) {
    const float4* p = (const float4*)(ea + (size_t)r * EDv);
#pragma unroll
    for (int q = 0; q < 4; q++) {
      float4 v = p[q];
      acc[q * 4 + 0] += v.x; acc[q * 4 + 1] += v.y;
      acc[q * 4 + 2] += v.z; acc[q * 4 + 3] += v.w;
    }
  }
  __shared__ float red[4][EDv];
  int wid = threadIdx.x >> 6, lane = threadIdx.x & 63;
#pragma unroll
  for (int d = 0; d < EDv; d++) {
    float v = acc[d];
    for (int off = 32; off; off >>= 1) v += __shfl_down(v, off, 64);
    if (lane == 0) red[wid][d] = v;
  }
  __syncthreads();
  if (threadIdx.x < EDv) {
    float v = red[0][threadIdx.x] + red[1][threadIdx.x] + red[2][threadIdx.x] + red[3][threadIdx.x];
    partials[blockIdx.x * EDv + threadIdx.x] = v;
  }
}

__global__ void mean_fold_kernel(const float* __restrict__ partials, float* __restrict__ mean_sum) {
  int tid = threadIdx.x;
  int d = tid & 15, r0 = tid >> 4;
  float v = 0.f;
  for (int r = r0; r < MEANBLK; r += 16) v += partials[r * EDv + d];
  __shared__ float buf[256];
  buf[tid] = v;
  __syncthreads();
  if (r0 < 8) buf[tid] += buf[tid + 128];
  __syncthreads();
  if (r0 < 4) buf[tid] += buf[tid + 64];
  __syncthreads();
  if (r0 < 2) buf[tid] += buf[tid + 32];
  __syncthreads();
  if (r0 == 0) mean_sum[d] = buf[tid] + buf[tid + 16];
}

// ---------------------------------------------------------------- v = fold(We, a_e), loop_al_e
__global__ void vloop_kernel(const float* __restrict__ We, const float* __restrict__ a_e,
                             const float* __restrict__ mean_sum,
                             float* __restrict__ v, float* __restrict__ loop_al_e) {
  int t = threadIdx.x;  // 64 threads
  int d = t >> 2, h = t & 3;
  float s = 0.f;
  for (int c = 0; c < CHv; c++) s += We[(size_t)d * HCv + h * CHv + c] * a_e[h * CHv + c];
  v[d * 4 + h] = s;
  __syncthreads();
  if (t < NHv) {
    float acc = 0.f;
    for (int d2 = 0; d2 < EDv; d2++) acc += (mean_sum[d2] * (1.0f / NEDGE)) * v[d2 * 4 + t];
    loop_al_e[t] = acc;
  }
}

// ---------------------------------------------------------------- al_e = ea @ v   [E,4]
__global__ void ale_kernel(const float* __restrict__ ea, const float* __restrict__ v,
                           float* __restrict__ al_e) {
  __shared__ float sv[EDv * NHv];
  if (threadIdx.x < EDv * NHv) sv[threadIdx.x] = v[threadIdx.x];
  __syncthreads();
  int e = blockIdx.x * blockDim.x + threadIdx.x;
  if (e >= NEDGE) return;
  const float4* p = (const float4*)(ea + (size_t)e * EDv);
  float row[16];
  *(float4*)&row[0] = p[0]; *(float4*)&row[4] = p[1];
  *(float4*)&row[8] = p[2]; *(float4*)&row[12] = p[3];
  float o0 = 0, o1 = 0, o2 = 0, o3 = 0;
#pragma unroll
  for (int d = 0; d < 16; d++) {
    o0 += row[d] * sv[d * 4 + 0];
    o1 += row[d] * sv[d * 4 + 1];
    o2 += row[d] * sv[d * 4 + 2];
    o3 += row[d] * sv[d * 4 + 3];
  }
  ((float4*)al_e)[e] = make_float4(o0, o1, o2, o3);
}

// ---------------------------------------------------------------- conversions
__global__ void conv_bf16_kernel(const float* __restrict__ in, ushort* __restrict__ out, int n4) {
  int i = blockIdx.x * 256 + threadIdx.x;
  if (i >= n4) return;
  float4 v = ((const float4*)in)[i];
  ushort4 o;
  o.x = f2b(v.x); o.y = f2b(v.y); o.z = f2b(v.z); o.w = f2b(v.w);
  ((ushort4*)out)[i] = o;
}

// W: [K][512] f32 -> Bt: [512][K] bf16
__global__ void wt_kernel(const float* __restrict__ W, ushort* __restrict__ Bt, int K) {
  int idx = blockIdx.x * 256 + threadIdx.x;
  if (idx >= K * HCv) return;
  int k = idx >> 9, n = idx & (HCv - 1);
  Bt[(size_t)n * K + k] = f2b(W[idx]);
}

// ---------------------------------------------------------------- bf16 MFMA GEMM
// C[M,512] = A[M,K](bf16) @ B[K,512], B given as Bt[512][K] bf16.
// Tile 128x128, BK=32, 4 waves (2x2), each wave 64x64 via 4x4 mfma_16x16x32.
// LDS layout fragment-packed: As[kq][m][8], Bs[kq][n][8] — contiguous for
// global_load_lds(16B), 2-way-free ds_read_b128 fragment reads.
__global__ __launch_bounds__(256) void gemm_mfma_kernel(const ushort* __restrict__ A,
                                                        const ushort* __restrict__ Bt,
                                                        float* __restrict__ C, int M, int K) {
  __shared__ ushort As[4][128][8];  // 8 KB
  __shared__ ushort Bs[4][128][8];  // 8 KB
  int tid = threadIdx.x;
  int wid = tid >> 6, lane = tid & 63;
  int rb = blockIdx.y * 128, cb = blockIdx.x * 128;
  int wm = (wid >> 1) * 64, wn = (wid & 1) * 64;
  int lr = lane & 15, lq = lane >> 4;

  f32x4 acc[4][4];
#pragma unroll
  for (int i = 0; i < 4; i++)
#pragma unroll
    for (int j = 0; j < 4; j++) acc[i][j] = (f32x4){0.f, 0.f, 0.f, 0.f};

  ushort* AsF = &As[0][0][0];
  ushort* BsF = &Bs[0][0][0];

  for (int k0 = 0; k0 < K; k0 += 32) {
#pragma unroll
    for (int s = 0; s < 2; s++) {
      int c = s * 256 + tid;        // chunk = kq*128 + m
      int kq = c >> 7, m = c & 127;
      int row = rb + m; if (row >= M) row = M - 1;
      const ushort* gA = A + (size_t)row * K + k0 + kq * 8;
      __builtin_amdgcn_global_load_lds((glb_u32*)gA, (lds_u32*)(AsF + (size_t)c * 8), 16, 0, 0);
    }
#pragma unroll
    for (int s = 0; s < 2; s++) {
      int c = s * 256 + tid;        // chunk = kq*128 + n
      int kq = c >> 7, n = c & 127;
      const ushort* gB = Bt + (size_t)(cb + n) * K + k0 + kq * 8;
      __builtin_amdgcn_global_load_lds((glb_u32*)gB, (lds_u32*)(BsF + (size_t)c * 8), 16, 0, 0);
    }
    __syncthreads();
    bf16x8 af[4], bfr[4];
#pragma unroll
    for (int i = 0; i < 4; i++) {
      af[i]  = *(const bf16x8*)&As[lq][wm + i * 16 + lr][0];
      bfr[i] = *(const bf16x8*)&Bs[lq][wn + i * 16 + lr][0];
    }
#pragma unroll
    for (int i = 0; i < 4; i++)
#pragma unroll
      for (int j = 0; j < 4; j++)
        acc[i][j] = __builtin_amdgcn_mfma_f32_16x16x32_bf16(af[i], bfr[j], acc[i][j], 0, 0, 0);
    __syncthreads();
  }

#pragma unroll
  for (int i = 0; i < 4; i++) {
    int rbase = rb + wm + i * 16 + lq * 4;
#pragma unroll
    for (int j = 0; j < 4; j++) {
      int col = cb + wn + j * 16 + lr;
#pragma unroll
      for (int r = 0; r < 4; r++) {
        int row = rbase + r;
        if (row < M) C[(size_t)row * HCv + col] = acc[i][j][r];
      }
    }
  }
}

// ---------------------------------------------------------------- al_src/al_dst from h
__global__ void rowdots_kernel(const float* __restrict__ h, const float* __restrict__ a_src,
                               const float* __restrict__ a_dst, float* __restrict__ al_src,
                               float* __restrict__ al_dst) {
  __shared__ float ssrc[HCv], sdst[HCv];
  int tid = threadIdx.x;  // 256
  for (int i = tid; i < HCv; i += 256) { ssrc[i] = a_src[i]; sdst[i] = a_dst[i]; }
  __syncthreads();
  int wave = tid >> 6, lane = tid & 63;
  int n = blockIdx.x * 4 + wave;
  if (n >= NNODE) return;
  const float4* hp = (const float4*)(h + (size_t)n * HCv);
  float s1 = 0.f, s2 = 0.f;
#pragma unroll
  for (int q = 0; q < 2; q++) {
    float4 v = hp[lane * 2 + q];
    int base = lane * 8 + q * 4;
    s1 += v.x * ssrc[base] + v.y * ssrc[base + 1] + v.z * ssrc[base + 2] + v.w * ssrc[base + 3];
    s2 += v.x * sdst[base] + v.y * sdst[base + 1] + v.z * sdst[base + 2] + v.w * sdst[base + 3];
  }
  for (int off = 8; off; off >>= 1) {
    s1 += __shfl_down(s1, off, 64);
    s2 += __shfl_down(s2, off, 64);
  }
  if ((lane & 15) == 0) {
    int head = lane >> 4;
    al_src[n * 4 + head] = s1;
    al_dst[n * 4 + head] = s2;
  }
}

// ---------------------------------------------------------------- per-node softmax + aggregate
#define CHKv 64
__global__ __launch_bounds__(256) void node_kernel(
    const float* __restrict__ h, const float* __restrict__ al_src,
    const float* __restrict__ al_dst, const float* __restrict__ al_e,
    const float* __restrict__ loop_al_e, const int* __restrict__ row_ptr,
    const int* __restrict__ src_sorted, const int* __restrict__ eid_sorted,
    const float* __restrict__ bias, float* __restrict__ outf, ushort* __restrict__ outb) {
  int n = blockIdx.x;
  int tid = threadIdx.x;
  int base = row_ptr[n];
  int deg = row_ptr[n + 1] - base;
  int wid = tid >> 6, lane = tid & 63;

  __shared__ int ssrc[CHKv];
  __shared__ float sw[CHKv][4];
  __shared__ float wm[4][4];
  __shared__ float wd[4][4];

  float4 aldv = *(const float4*)(al_dst + (size_t)n * 4);
  float ald[4] = {aldv.x, aldv.y, aldv.z, aldv.w};

  float alp[4];
  {
    float4 as = *(const float4*)(al_src + (size_t)n * 4);
    float aa[4] = {as.x, as.y, as.z, as.w};
#pragma unroll
    for (int hh = 0; hh < 4; hh++) {
      float a = aa[hh] + ald[hh] + loop_al_e[hh];
      alp[hh] = a > 0.f ? a : SLOPEv * a;
    }
  }

  // ---- pass A: per-head max
  float mx[4] = {alp[0], alp[1], alp[2], alp[3]};
  for (int i = tid; i < deg; i += 256) {
    int s = src_sorted[base + i];
    int e = eid_sorted[base + i];
    float4 as = *(const float4*)(al_src + (size_t)s * 4);
    float4 ae = *(const float4*)(al_e + (size_t)e * 4);
    float av[4] = {as.x + ald[0] + ae.x, as.y + ald[1] + ae.y,
                   as.z + ald[2] + ae.z, as.w + ald[3] + ae.w};
#pragma unroll
    for (int hh = 0; hh < 4; hh++) {
      float a = av[hh] > 0.f ? av[hh] : SLOPEv * av[hh];
      mx[hh] = fmaxf(mx[hh], a);
    }
  }
#pragma unroll
  for (int hh = 0; hh < 4; hh++) {
    float v = mx[hh];
    for (int off = 32; off; off >>= 1) v = fmaxf(v, __shfl_down(v, off, 64));
    if (lane == 0) wm[wid][hh] = v;
  }
  __syncthreads();
  float m[4];
#pragma unroll
  for (int hh = 0; hh < 4; hh++)
    m[hh] = fmaxf(fmaxf(wm[0][hh], wm[1][hh]), fmaxf(wm[2][hh], wm[3][hh]));

  // ---- pass B: chunked exp + weighted gather
  int c0 = tid, c1 = tid + 256;
  int h0 = c0 >> 7, h1 = c1 >> 7;
  float acc0 = 0.f, acc1 = 0.f;
  float dpart[4] = {0.f, 0.f, 0.f, 0.f};

  for (int cs = 0; cs < deg; cs += CHKv) {
    int cl = min(CHKv, deg - cs);
    __syncthreads();
    if (tid < cl) {
      int s = src_sorted[base + cs + tid];
      int e = eid_sorted[base + cs + tid];
      float4 as = *(const float4*)(al_src + (size_t)s * 4);
      float4 ae = *(const float4*)(al_e + (size_t)e * 4);
      float av[4] = {as.x + ald[0] + ae.x, as.y + ald[1] + ae.y,
                     as.z + ald[2] + ae.z, as.w + ald[3] + ae.w};
      ssrc[tid] = s;
#pragma unroll
      for (int hh = 0; hh < 4; hh++) {
        float a = av[hh] > 0.f ? av[hh] : SLOPEv * av[hh];
        float w = expf(a - m[hh]);
        sw[tid][hh] = w;
        dpart[hh] += w;
      }
    }
    __syncthreads();
#pragma unroll 4
    for (int j = 0; j < cl; j++) {
      int s = ssrc[j];
      float w0 = sw[j][h0], w1 = sw[j][h1];
      acc0 = fmaf(w0, h[(size_t)s * HCv + c0], acc0);
      acc1 = fmaf(w1, h[(size_t)s * HCv + c1], acc1);
    }
  }

  float wl[4];
#pragma unroll
  for (int hh = 0; hh < 4; hh++) wl[hh] = expf(alp[hh] - m[hh]);
  if (tid == 0) {
#pragma unroll
    for (int hh = 0; hh < 4; hh++) dpart[hh] += wl[hh];
  }
  acc0 = fmaf(wl[h0], h[(size_t)n * HCv + c0], acc0);
  acc1 = fmaf(wl[h1], h[(size_t)n * HCv + c1], acc1);

#pragma unroll
  for (int hh = 0; hh < 4; hh++) {
    float v = dpart[hh];
    for (int off = 32; off; off >>= 1) v += __shfl_down(v, off, 64);
    if (lane == 0) wd[wid][hh] = v;
  }
  __syncthreads();
  float den0 = wd[0][h0] + wd[1][h0] + wd[2][h0] + wd[3][h0];
  float den1 = wd[0][h1] + wd[1][h1] + wd[2][h1] + wd[3][h1];

  float r0 = acc0 / (den0 + 1e-16f) + bias[c0];
  float r1 = acc1 / (den1 + 1e-16f) + bias[c1];
  r0 = r0 > 0.f ? r0 : expm1f(r0);
  r1 = r1 > 0.f ? r1 : expm1f(r1);
  if (outf) {
    outf[(size_t)n * HCv + c0] = r0;
    outf[(size_t)n * HCv + c1] = r1;
  }
  if (outb) {
    outb[(size_t)n * HCv + c0] = f2b(r0);
    outb[(size_t)n * HCv + c1] = f2b(r1);
  }
}

// ---------------------------------------------------------------- launch
static inline char* take(char*& p, size_t bytes) {
  char* r = p;
  p += (bytes + 255) & ~(size_t)255;
  return r;
}

extern "C" void kernel_launch(void* const* d_in, const int* in_sizes, int n_in,
                              void* d_out, int out_size, void* d_ws, size_t ws_size,
                              hipStream_t stream) {
  (void)in_sizes; (void)n_in; (void)out_size; (void)ws_size;
  const float* x   = (const float*)d_in[0];
  const int*   ei  = (const int*)d_in[1];
  const float* ea  = (const float*)d_in[2];
  const float* W1  = (const float*)d_in[3];
  const float* as1 = (const float*)d_in[4];
  const float* ad1 = (const float*)d_in[5];
  const float* We1 = (const float*)d_in[6];
  const float* ae1 = (const float*)d_in[7];
  const float* b1  = (const float*)d_in[8];
  const float* W2  = (const float*)d_in[9];
  const float* as2 = (const float*)d_in[10];
  const float* ad2 = (const float*)d_in[11];
  const float* We2 = (const float*)d_in[12];
  const float* ae2 = (const float*)d_in[13];
  const float* b2  = (const float*)d_in[14];
  float* out = (float*)d_out;

  char* p = (char*)d_ws;
  float* h          = (float*)take(p, (size_t)NNODE * HCv * 4);
  float* al_src     = (float*)take(p, (size_t)NNODE * 4 * 4);
  float* al_dst     = (float*)take(p, (size_t)NNODE * 4 * 4);
  float* al_e       = (float*)take(p, (size_t)NEDGE * 4 * 4);
  int*   src_sorted = (int*)take(p, (size_t)NEDGE * 4);
  int*   eid_sorted = (int*)take(p, (size_t)NEDGE * 4);
  int*   row_ptr    = (int*)take(p, (size_t)(NNODE + 1) * 4);
  float* partials   = (float*)take(p, (size_t)MEANBLK * EDv * 4);
  ushort* Bt1       = (ushort*)take(p, (size_t)HCv * DINv * 2);
  ushort* Bt2       = (ushort*)take(p, (size_t)HCv * HCv * 2);
  char* zero_begin = p;
  int*   deg        = (int*)take(p, (size_t)NNODE * 4);
  int*   cursor     = (int*)take(p, (size_t)NNODE * 4);
  size_t zero_len = (size_t)(p - zero_begin);
  float* mean_sum   = (float*)take(p, 16 * 4);
  float* v          = (float*)take(p, 64 * 4);
  float* loop_ale   = (float*)take(p, 4 * 4);
  int*   flag       = (int*)take(p, 4);

  // scratch carved out of d_out (102.4 MB; final write happens after all reads)
  ushort* xb  = (ushort*)d_out;                                  // 12.8 MB
  ushort* h1b = (ushort*)((char*)d_out + (size_t)16 * 1024 * 1024);  // 51.2 MB

  hipMemsetAsync(zero_begin, 0, zero_len, stream);

  detect_kernel<<<1, 256, 0, stream>>>(ei, flag);
  count_kernel<<<(NEDGE + 255) / 256, 256, 0, stream>>>(ei, flag, deg);
  scan_kernel<<<1, 1024, 0, stream>>>(deg, row_ptr);
  scatter_kernel<<<(NEDGE + 255) / 256, 256, 0, stream>>>(ei, flag, row_ptr, cursor,
                                                          src_sorted, eid_sorted);
  mean_part_kernel<<<MEANBLK, 256, 0, stream>>>(ea, partials);
  mean_fold_kernel<<<1, 256, 0, stream>>>(partials, mean_sum);

  // conversions (independent of CSR)
  conv_bf16_kernel<<<(NNODE * DINv / 4 + 255) / 256, 256, 0, stream>>>(x, xb, NNODE * DINv / 4);
  wt_kernel<<<(DINv * HCv + 255) / 256, 256, 0, stream>>>(W1, Bt1, DINv);
  wt_kernel<<<(HCv * HCv + 255) / 256, 256, 0, stream>>>(W2, Bt2, HCv);

  // ---- layer 1
  vloop_kernel<<<1, 64, 0, stream>>>(We1, ae1, mean_sum, v, loop_ale);
  ale_kernel<<<(NEDGE + 255) / 256, 256, 0, stream>>>(ea, v, al_e);
  gemm_mfma_kernel<<<dim3(HCv / 128, (NNODE + 127) / 128), 256, 0, stream>>>(xb, Bt1, h, NNODE, DINv);
  rowdots_kernel<<<(NNODE + 3) / 4, 256, 0, stream>>>(h, as1, ad1, al_src, al_dst);
  node_kernel<<<NNODE, 256, 0, stream>>>(h, al_src, al_dst, al_e, loop_ale, row_ptr,
                                         src_sorted, eid_sorted, b1, (float*)nullptr, h1b);

  // ---- layer 2
  vloop_kernel<<<1, 64, 0, stream>>>(We2, ae2, mean_sum, v, loop_ale);
  ale_kernel<<<(NEDGE + 255) / 256, 256, 0, stream>>>(ea, v, al_e);
  gemm_mfma_kernel<<<dim3(HCv / 128, (NNODE + 127) / 128), 256, 0, stream>>>(h1b, Bt2, h, NNODE, HCv);
  rowdots_kernel<<<(NNODE + 3) / 4, 256, 0, stream>>>(h, as2, ad2, al_src, al_dst);
  node_kernel<<<NNODE, 256, 0, stream>>>(h, al_src, al_dst, al_e, loop_ale, row_ptr,
                                         src_sorted, eid_sorted, b2, out, (ushort*)nullptr);
}

// Round 4
// 927.070 us; speedup vs baseline: 1.9480x; 1.1418x over previous
//
#include <hip/hip_runtime.h>
#include <math.h>

#define NNODE 50000
#define NEDGE 800000
#define DINv  128
#define EDv   16
#define NHv   4
#define CHv   128
#define HCv   512
#define SLOPEv 0.2f
#define MEANBLK 512

typedef __attribute__((ext_vector_type(8))) short bf16x8;
typedef __attribute__((ext_vector_type(4))) float f32x4;
typedef __attribute__((address_space(3))) unsigned lds_u32;
typedef const __attribute__((address_space(1))) unsigned glb_u32;

__device__ __forceinline__ ushort f2b(float f) {
  unsigned u = __float_as_uint(f);
  u += 0x7FFF + ((u >> 16) & 1);
  return (ushort)(u >> 16);
}
__device__ __forceinline__ float blo(unsigned u) { return __uint_as_float(u << 16); }
__device__ __forceinline__ float bhi(unsigned u) { return __uint_as_float(u & 0xffff0000u); }

// ---------------------------------------------------------------- CSR build
__global__ void detect_kernel(const int* __restrict__ ei, int* __restrict__ flag) {
  __shared__ int bad;
  if (threadIdx.x == 0) bad = 0;
  __syncthreads();
  for (int i = threadIdx.x; i < 2048; i += 256)
    if (ei[2 * i + 1] != 0) bad = 1;
  __syncthreads();
  if (threadIdx.x == 0) flag[0] = bad ? 0 : 1;
}

__device__ __forceinline__ int load_idx(const int* __restrict__ ei, int e, int row, int wide) {
  if (wide) return ei[2 * ((size_t)row * NEDGE + e)];
  return ei[(size_t)row * NEDGE + e];
}

__global__ void count_kernel(const int* __restrict__ ei, const int* __restrict__ flag,
                             int* __restrict__ deg) {
  int e = blockIdx.x * blockDim.x + threadIdx.x;
  if (e < NEDGE) {
    int w = flag[0];
    atomicAdd(&deg[load_idx(ei, e, 1, w)], 1);
  }
}

__global__ __launch_bounds__(1024) void scan_kernel(const int* __restrict__ deg,
                                                    int* __restrict__ row_ptr) {
  __shared__ int buf[1024];
  __shared__ int carry;
  int tid = threadIdx.x;
  if (tid == 0) carry = 0;
  __syncthreads();
  for (int base = 0; base < NNODE; base += 1024) {
    int x = (base + tid < NNODE) ? deg[base + tid] : 0;
    buf[tid] = x;
    __syncthreads();
    for (int off = 1; off < 1024; off <<= 1) {
      int t = (tid >= off) ? buf[tid - off] : 0;
      __syncthreads();
      buf[tid] += t;
      __syncthreads();
    }
    if (base + tid < NNODE) row_ptr[base + tid] = carry + buf[tid] - x;
    __syncthreads();
    if (tid == 0) carry += buf[1023];
    __syncthreads();
  }
  if (tid == 0) row_ptr[NNODE] = carry;
}

__global__ void scatter_kernel(const int* __restrict__ ei, const int* __restrict__ flag,
                               const int* __restrict__ row_ptr, int* __restrict__ cursor,
                               int* __restrict__ src_sorted, int* __restrict__ eid_sorted) {
  int e = blockIdx.x * blockDim.x + threadIdx.x;
  if (e < NEDGE) {
    int w = flag[0];
    int d = load_idx(ei, e, 1, w);
    int s = load_idx(ei, e, 0, w);
    int p = row_ptr[d] + atomicAdd(&cursor[d], 1);
    src_sorted[p] = s;
    eid_sorted[p] = e;
  }
}

// ---------------------------------------------------------------- mean(edge_features)
__global__ void mean_part_kernel(const float* __restrict__ ea, float* __restrict__ partials) {
  float acc[EDv];
#pragma unroll
  for (int d = 0; d < EDv; d++) acc[d] = 0.f;
  int stride = gridDim.x * blockDim.x;
  for (int r = blockIdx.x * blockDim.x + threadIdx.x; r < NEDGE; r += stride) {
    const float4* p = (const float4*)(ea + (size_t)r * EDv);
#pragma unroll
    for (int q = 0; q < 4; q++) {
      float4 v = p[q];
      acc[q * 4 + 0] += v.x; acc[q * 4 + 1] += v.y;
      acc[q * 4 + 2] += v.z; acc[q * 4 + 3] += v.w;
    }
  }
  __shared__ float red[4][EDv];
  int wid = threadIdx.x >> 6, lane = threadIdx.x & 63;
#pragma unroll
  for (int d = 0; d < EDv; d++) {
    float v = acc[d];
    for (int off = 32; off; off >>= 1) v += __shfl_down(v, off, 64);
    if (lane == 0) red[wid][d] = v;
  }
  __syncthreads();
  if (threadIdx.x < EDv) {
    float v = red[0][threadIdx.x] + red[1][threadIdx.x] + red[2][threadIdx.x] + red[3][threadIdx.x];
    partials[blockIdx.x * EDv + threadIdx.x] = v;
  }
}

__global__ void mean_fold_kernel(const float* __restrict__ partials, float* __restrict__ mean_sum) {
  int tid = threadIdx.x;
  int d = tid & 15, r0 = tid >> 4;
  float v = 0.f;
  for (int r = r0; r < MEANBLK; r += 16) v += partials[r * EDv + d];
  __shared__ float buf[256];
  buf[tid] = v;
  __syncthreads();
  if (r0 < 8) buf[tid] += buf[tid + 128];
  __syncthreads();
  if (r0 < 4) buf[tid] += buf[tid + 64];
  __syncthreads();
  if (r0 < 2) buf[tid] += buf[tid + 32];
  __syncthreads();
  if (r0 == 0) mean_sum[d] = buf[tid] + buf[tid + 16];
}

// ---------------------------------------------------------------- v = fold(We, a_e), loop_al_e
__global__ void vloop_kernel(const float* __restrict__ We, const float* __restrict__ a_e,
                             const float* __restrict__ mean_sum,
                             float* __restrict__ v, float* __restrict__ loop_al_e) {
  int t = threadIdx.x;  // 64 threads
  int d = t >> 2, h = t & 3;
  float s = 0.f;
  for (int c = 0; c < CHv; c++) s += We[(size_t)d * HCv + h * CHv + c] * a_e[h * CHv + c];
  v[d * 4 + h] = s;
  __syncthreads();
  if (t < NHv) {
    float acc = 0.f;
    for (int d2 = 0; d2 < EDv; d2++) acc += (mean_sum[d2] * (1.0f / NEDGE)) * v[d2 * 4 + t];
    loop_al_e[t] = acc;
  }
}

// ---------------------------------------------------------------- al_e = ea @ v   [E,4]
__global__ void ale_kernel(const float* __restrict__ ea, const float* __restrict__ v,
                           float* __restrict__ al_e) {
  __shared__ float sv[EDv * NHv];
  if (threadIdx.x < EDv * NHv) sv[threadIdx.x] = v[threadIdx.x];
  __syncthreads();
  int e = blockIdx.x * blockDim.x + threadIdx.x;
  if (e >= NEDGE) return;
  const float4* p = (const float4*)(ea + (size_t)e * EDv);
  float row[16];
  *(float4*)&row[0] = p[0]; *(float4*)&row[4] = p[1];
  *(float4*)&row[8] = p[2]; *(float4*)&row[12] = p[3];
  float o0 = 0, o1 = 0, o2 = 0, o3 = 0;
#pragma unroll
  for (int d = 0; d < 16; d++) {
    o0 += row[d] * sv[d * 4 + 0];
    o1 += row[d] * sv[d * 4 + 1];
    o2 += row[d] * sv[d * 4 + 2];
    o3 += row[d] * sv[d * 4 + 3];
  }
  ((float4*)al_e)[e] = make_float4(o0, o1, o2, o3);
}

// ---------------------------------------------------------------- ap[p] = al_src[src[p]] + al_e[eid[p]]
__global__ void apre_kernel(const int* __restrict__ src_sorted, const int* __restrict__ eid_sorted,
                            const float* __restrict__ al_src, const float* __restrict__ al_e,
                            float* __restrict__ ap) {
  int p = blockIdx.x * 256 + threadIdx.x;
  if (p >= NEDGE) return;
  int s = src_sorted[p];
  int e = eid_sorted[p];
  float4 a = ((const float4*)al_src)[s];
  float4 b = ((const float4*)al_e)[e];
  ((float4*)ap)[p] = make_float4(a.x + b.x, a.y + b.y, a.z + b.z, a.w + b.w);
}

// ---------------------------------------------------------------- conversions
__global__ void conv_bf16_kernel(const float* __restrict__ in, ushort* __restrict__ out, int n4) {
  int i = blockIdx.x * 256 + threadIdx.x;
  if (i >= n4) return;
  float4 v = ((const float4*)in)[i];
  ushort4 o;
  o.x = f2b(v.x); o.y = f2b(v.y); o.z = f2b(v.z); o.w = f2b(v.w);
  ((ushort4*)out)[i] = o;
}

// W: [K][512] f32 -> Bt: [512][K] bf16
__global__ void wt_kernel(const float* __restrict__ W, ushort* __restrict__ Bt, int K) {
  int idx = blockIdx.x * 256 + threadIdx.x;
  if (idx >= K * HCv) return;
  int k = idx >> 9, n = idx & (HCv - 1);
  Bt[(size_t)n * K + k] = f2b(W[idx]);
}

// ---------------------------------------------------------------- bf16 MFMA GEMM, bf16 output
__global__ __launch_bounds__(256) void gemm_mfma_kernel(const ushort* __restrict__ A,
                                                        const ushort* __restrict__ Bt,
                                                        ushort* __restrict__ C, int M, int K) {
  __shared__ ushort As[4][128][8];  // 8 KB
  __shared__ ushort Bs[4][128][8];  // 8 KB
  int tid = threadIdx.x;
  int wid = tid >> 6, lane = tid & 63;
  int rb = blockIdx.y * 128, cb = blockIdx.x * 128;
  int wm = (wid >> 1) * 64, wn = (wid & 1) * 64;
  int lr = lane & 15, lq = lane >> 4;

  f32x4 acc[4][4];
#pragma unroll
  for (int i = 0; i < 4; i++)
#pragma unroll
    for (int j = 0; j < 4; j++) acc[i][j] = (f32x4){0.f, 0.f, 0.f, 0.f};

  ushort* AsF = &As[0][0][0];
  ushort* BsF = &Bs[0][0][0];

  for (int k0 = 0; k0 < K; k0 += 32) {
#pragma unroll
    for (int s = 0; s < 2; s++) {
      int c = s * 256 + tid;        // chunk = kq*128 + m
      int kq = c >> 7, m = c & 127;
      int row = rb + m; if (row >= M) row = M - 1;
      const ushort* gA = A + (size_t)row * K + k0 + kq * 8;
      __builtin_amdgcn_global_load_lds((glb_u32*)gA, (lds_u32*)(AsF + (size_t)c * 8), 16, 0, 0);
    }
#pragma unroll
    for (int s = 0; s < 2; s++) {
      int c = s * 256 + tid;        // chunk = kq*128 + n
      int kq = c >> 7, n = c & 127;
      const ushort* gB = Bt + (size_t)(cb + n) * K + k0 + kq * 8;
      __builtin_amdgcn_global_load_lds((glb_u32*)gB, (lds_u32*)(BsF + (size_t)c * 8), 16, 0, 0);
    }
    __syncthreads();
    bf16x8 af[4], bfr[4];
#pragma unroll
    for (int i = 0; i < 4; i++) {
      af[i]  = *(const bf16x8*)&As[lq][wm + i * 16 + lr][0];
      bfr[i] = *(const bf16x8*)&Bs[lq][wn + i * 16 + lr][0];
    }
#pragma unroll
    for (int i = 0; i < 4; i++)
#pragma unroll
      for (int j = 0; j < 4; j++)
        acc[i][j] = __builtin_amdgcn_mfma_f32_16x16x32_bf16(af[i], bfr[j], acc[i][j], 0, 0, 0);
    __syncthreads();
  }

#pragma unroll
  for (int i = 0; i < 4; i++) {
    int rbase = rb + wm + i * 16 + lq * 4;
#pragma unroll
    for (int j = 0; j < 4; j++) {
      int col = cb + wn + j * 16 + lr;
#pragma unroll
      for (int r = 0; r < 4; r++) {
        int row = rbase + r;
        if (row < M) C[(size_t)row * HCv + col] = f2b(acc[i][j][r]);
      }
    }
  }
}

// ---------------------------------------------------------------- al_src/al_dst from bf16 h
__global__ void rowdots_kernel(const ushort* __restrict__ hb, const float* __restrict__ a_src,
                               const float* __restrict__ a_dst, float* __restrict__ al_src,
                               float* __restrict__ al_dst) {
  __shared__ float ssrc[HCv], sdst[HCv];
  int tid = threadIdx.x;  // 256
  for (int i = tid; i < HCv; i += 256) { ssrc[i] = a_src[i]; sdst[i] = a_dst[i]; }
  __syncthreads();
  int wave = tid >> 6, lane = tid & 63;
  int n = blockIdx.x * 4 + wave;
  if (n >= NNODE) return;
  const uint4* hp = (const uint4*)(hb + (size_t)n * HCv);
  uint4 u = hp[lane];  // 8 bf16: cols lane*8 .. lane*8+7
  int base = lane * 8;
  float f[8] = {blo(u.x), bhi(u.x), blo(u.y), bhi(u.y), blo(u.z), bhi(u.z), blo(u.w), bhi(u.w)};
  float s1 = 0.f, s2 = 0.f;
#pragma unroll
  for (int q = 0; q < 8; q++) {
    s1 = fmaf(f[q], ssrc[base + q], s1);
    s2 = fmaf(f[q], sdst[base + q], s2);
  }
  for (int off = 8; off; off >>= 1) {
    s1 += __shfl_down(s1, off, 64);
    s2 += __shfl_down(s2, off, 64);
  }
  if ((lane & 15) == 0) {
    int head = lane >> 4;
    al_src[n * 4 + head] = s1;
    al_dst[n * 4 + head] = s2;
  }
}

// ---------------------------------------------------------------- per-node softmax + aggregate
// thread t handles columns 2t, 2t+1 (same head = wave id); h gathered as bf16 pairs
#define CHKv 64
__global__ __launch_bounds__(256) void node_kernel(
    const ushort* __restrict__ hb, const float* __restrict__ al_src,
    const float* __restrict__ al_dst, const float* __restrict__ ap,
    const float* __restrict__ loop_al_e, const int* __restrict__ row_ptr,
    const int* __restrict__ src_sorted, const float* __restrict__ bias,
    float* __restrict__ outf, ushort* __restrict__ outb) {
  int n = blockIdx.x;
  int tid = threadIdx.x;
  int base = row_ptr[n];
  int deg = row_ptr[n + 1] - base;
  int wid = tid >> 6, lane = tid & 63;

  __shared__ int ssrc[CHKv];
  __shared__ float sw[CHKv][4];
  __shared__ float wm[4][4];
  __shared__ float wd[4][4];

  float4 aldv = *(const float4*)(al_dst + (size_t)n * 4);
  float ald[4] = {aldv.x, aldv.y, aldv.z, aldv.w};

  float alp[4];
  {
    float4 as = *(const float4*)(al_src + (size_t)n * 4);
    float aa[4] = {as.x, as.y, as.z, as.w};
#pragma unroll
    for (int hh = 0; hh < 4; hh++) {
      float a = aa[hh] + ald[hh] + loop_al_e[hh];
      alp[hh] = a > 0.f ? a : SLOPEv * a;
    }
  }

  // ---- pass A: per-head max over edges (sequential ap reads)
  float mx[4] = {alp[0], alp[1], alp[2], alp[3]};
  for (int i = tid; i < deg; i += 256) {
    float4 t = ((const float4*)ap)[base + i];
    float av[4] = {t.x + ald[0], t.y + ald[1], t.z + ald[2], t.w + ald[3]};
#pragma unroll
    for (int hh = 0; hh < 4; hh++) {
      float a = av[hh] > 0.f ? av[hh] : SLOPEv * av[hh];
      mx[hh] = fmaxf(mx[hh], a);
    }
  }
#pragma unroll
  for (int hh = 0; hh < 4; hh++) {
    float v = mx[hh];
    for (int off = 32; off; off >>= 1) v = fmaxf(v, __shfl_down(v, off, 64));
    if (lane == 0) wm[wid][hh] = v;
  }
  __syncthreads();
  float m[4];
#pragma unroll
  for (int hh = 0; hh < 4; hh++)
    m[hh] = fmaxf(fmaxf(wm[0][hh], wm[1][hh]), fmaxf(wm[2][hh], wm[3][hh]));

  // ---- pass B: chunked exp + weighted gather (bf16 pairs)
  float acc0 = 0.f, acc1 = 0.f;
  float dpart[4] = {0.f, 0.f, 0.f, 0.f};

  for (int cs = 0; cs < deg; cs += CHKv) {
    int cl = min(CHKv, deg - cs);
    __syncthreads();
    if (tid < cl) {
      float4 t = ((const float4*)ap)[base + cs + tid];
      float av[4] = {t.x + ald[0], t.y + ald[1], t.z + ald[2], t.w + ald[3]};
      ssrc[tid] = src_sorted[base + cs + tid];
#pragma unroll
      for (int hh = 0; hh < 4; hh++) {
        float a = av[hh] > 0.f ? av[hh] : SLOPEv * av[hh];
        float w = expf(a - m[hh]);
        sw[tid][hh] = w;
        dpart[hh] += w;
      }
    }
    __syncthreads();
#pragma unroll 4
    for (int j = 0; j < cl; j++) {
      int s = ssrc[j];
      float w = sw[j][wid];
      unsigned u = ((const unsigned*)(hb + (size_t)s * HCv))[tid];
      acc0 = fmaf(w, blo(u), acc0);
      acc1 = fmaf(w, bhi(u), acc1);
    }
  }

  float wl[4];
#pragma unroll
  for (int hh = 0; hh < 4; hh++) wl[hh] = expf(alp[hh] - m[hh]);
  if (tid == 0) {
#pragma unroll
    for (int hh = 0; hh < 4; hh++) dpart[hh] += wl[hh];
  }
  {
    unsigned u = ((const unsigned*)(hb + (size_t)n * HCv))[tid];
    acc0 = fmaf(wl[wid], blo(u), acc0);
    acc1 = fmaf(wl[wid], bhi(u), acc1);
  }

#pragma unroll
  for (int hh = 0; hh < 4; hh++) {
    float v = dpart[hh];
    for (int off = 32; off; off >>= 1) v += __shfl_down(v, off, 64);
    if (lane == 0) wd[wid][hh] = v;
  }
  __syncthreads();
  float den = wd[0][wid] + wd[1][wid] + wd[2][wid] + wd[3][wid];

  float2 bb = ((const float2*)bias)[tid];
  float r0 = acc0 / (den + 1e-16f) + bb.x;
  float r1 = acc1 / (den + 1e-16f) + bb.y;
  r0 = r0 > 0.f ? r0 : expm1f(r0);
  r1 = r1 > 0.f ? r1 : expm1f(r1);
  if (outf) {
    ((float2*)(outf + (size_t)n * HCv))[tid] = make_float2(r0, r1);
  }
  if (outb) {
    ((unsigned*)(outb + (size_t)n * HCv))[tid] = (unsigned)f2b(r0) | ((unsigned)f2b(r1) << 16);
  }
}

// ---------------------------------------------------------------- launch
static inline char* take(char*& p, size_t bytes) {
  char* r = p;
  p += (bytes + 255) & ~(size_t)255;
  return r;
}

extern "C" void kernel_launch(void* const* d_in, const int* in_sizes, int n_in,
                              void* d_out, int out_size, void* d_ws, size_t ws_size,
                              hipStream_t stream) {
  (void)in_sizes; (void)n_in; (void)out_size; (void)ws_size;
  const float* x   = (const float*)d_in[0];
  const int*   ei  = (const int*)d_in[1];
  const float* ea  = (const float*)d_in[2];
  const float* W1  = (const float*)d_in[3];
  const float* as1 = (const float*)d_in[4];
  const float* ad1 = (const float*)d_in[5];
  const float* We1 = (const float*)d_in[6];
  const float* ae1 = (const float*)d_in[7];
  const float* b1  = (const float*)d_in[8];
  const float* W2  = (const float*)d_in[9];
  const float* as2 = (const float*)d_in[10];
  const float* ad2 = (const float*)d_in[11];
  const float* We2 = (const float*)d_in[12];
  const float* ae2 = (const float*)d_in[13];
  const float* b2  = (const float*)d_in[14];
  float* out = (float*)d_out;

  char* p = (char*)d_ws;
  ushort* hb        = (ushort*)take(p, (size_t)NNODE * HCv * 2);
  float* al_src     = (float*)take(p, (size_t)NNODE * 4 * 4);
  float* al_dst     = (float*)take(p, (size_t)NNODE * 4 * 4);
  float* al_e       = (float*)take(p, (size_t)NEDGE * 4 * 4);
  float* ap         = (float*)take(p, (size_t)NEDGE * 4 * 4);
  int*   src_sorted = (int*)take(p, (size_t)NEDGE * 4);
  int*   eid_sorted = (int*)take(p, (size_t)NEDGE * 4);
  int*   row_ptr    = (int*)take(p, (size_t)(NNODE + 1) * 4);
  float* partials   = (float*)take(p, (size_t)MEANBLK * EDv * 4);
  ushort* Bt1       = (ushort*)take(p, (size_t)HCv * DINv * 2);
  ushort* Bt2       = (ushort*)take(p, (size_t)HCv * HCv * 2);
  char* zero_begin = p;
  int*   deg        = (int*)take(p, (size_t)NNODE * 4);
  int*   cursor     = (int*)take(p, (size_t)NNODE * 4);
  size_t zero_len = (size_t)(p - zero_begin);
  float* mean_sum   = (float*)take(p, 16 * 4);
  float* v          = (float*)take(p, 64 * 4);
  float* loop_ale   = (float*)take(p, 4 * 4);
  int*   flag       = (int*)take(p, 4);

  // scratch carved out of d_out (102.4 MB): xb dead after layer-1 gemm,
  // h1b dead after layer-2 gemm; final out written only by the last node_kernel.
  ushort* xb  = (ushort*)d_out;                                       // 12.8 MB
  ushort* h1b = (ushort*)((char*)d_out + (size_t)16 * 1024 * 1024);   // 51.2 MB

  hipMemsetAsync(zero_begin, 0, zero_len, stream);

  detect_kernel<<<1, 256, 0, stream>>>(ei, flag);
  count_kernel<<<(NEDGE + 255) / 256, 256, 0, stream>>>(ei, flag, deg);
  scan_kernel<<<1, 1024, 0, stream>>>(deg, row_ptr);
  scatter_kernel<<<(NEDGE + 255) / 256, 256, 0, stream>>>(ei, flag, row_ptr, cursor,
                                                          src_sorted, eid_sorted);
  mean_part_kernel<<<MEANBLK, 256, 0, stream>>>(ea, partials);
  mean_fold_kernel<<<1, 256, 0, stream>>>(partials, mean_sum);

  conv_bf16_kernel<<<(NNODE * DINv / 4 + 255) / 256, 256, 0, stream>>>(x, xb, NNODE * DINv / 4);
  wt_kernel<<<(DINv * HCv + 255) / 256, 256, 0, stream>>>(W1, Bt1, DINv);
  wt_kernel<<<(HCv * HCv + 255) / 256, 256, 0, stream>>>(W2, Bt2, HCv);

  // ---- layer 1
  vloop_kernel<<<1, 64, 0, stream>>>(We1, ae1, mean_sum, v, loop_ale);
  ale_kernel<<<(NEDGE + 255) / 256, 256, 0, stream>>>(ea, v, al_e);
  gemm_mfma_kernel<<<dim3(HCv / 128, (NNODE + 127) / 128), 256, 0, stream>>>(xb, Bt1, hb, NNODE, DINv);
  rowdots_kernel<<<(NNODE + 3) / 4, 256, 0, stream>>>(hb, as1, ad1, al_src, al_dst);
  apre_kernel<<<(NEDGE + 255) / 256, 256, 0, stream>>>(src_sorted, eid_sorted, al_src, al_e, ap);
  node_kernel<<<NNODE, 256, 0, stream>>>(hb, al_src, al_dst, ap, loop_ale, row_ptr,
                                         src_sorted, b1, (float*)nullptr, h1b);

  // ---- layer 2
  vloop_kernel<<<1, 64, 0, stream>>>(We2, ae2, mean_sum, v, loop_ale);
  ale_kernel<<<(NEDGE + 255) / 256, 256, 0, stream>>>(ea, v, al_e);
  gemm_mfma_kernel<<<dim3(HCv / 128, (NNODE + 127) / 128), 256, 0, stream>>>(h1b, Bt2, hb, NNODE, HCv);
  rowdots_kernel<<<(NNODE + 3) / 4, 256, 0, stream>>>(hb, as2, ad2, al_src, al_dst);
  apre_kernel<<<(NEDGE + 255) / 256, 256, 0, stream>>>(src_sorted, eid_sorted, al_src, al_e, ap);
  node_kernel<<<NNODE, 256, 0, stream>>>(hb, al_src, al_dst, ap, loop_ale, row_ptr,
                                         src_sorted, b2, out, (ushort*)nullptr);
}